// Round 1
// 881.148 us; speedup vs baseline: 1.0072x; 1.0072x over previous
//
#include <hip/hip_runtime.h>
#include <float.h>
#include <math.h>

#define DIM 512
#define VDIM 512
#define ROWS_PER_WAVE 32
#define WAVES_PER_BLOCK 4
#define CHUNK 4
#define NCHUNK (ROWS_PER_WAVE / CHUNK)

// Kernel A: one wave per 32-row chunk. Lane holds 8 floats of each row split as
// two fully-contiguous 1 KiB wave-segments (q[lane*4], q[256+lane*4]); full
// 64-lane shfl_xor butterfly gives every lane the dot product. Rows are
// processed in chunks of 4 with an explicit register double-buffer: the next
// chunk's 8 global loads are issued BEFORE the current chunk's reduce, so each
// wave keeps ~8 KiB outstanding instead of stalling with zero bytes in flight
// during the dependent shfl/exp chain (the prior version's break-terminated
// loop blocked this pipelining and left the kernel at ~2.5 TB/s).
__global__ __launch_bounds__(256) void logits_partials(
    const float* __restrict__ query,
    const float* __restrict__ keys,
    int n,
    float* __restrict__ pmax,
    float* __restrict__ psum,
    int*   __restrict__ pidx)
{
    const int lane = threadIdx.x & 63;
    const int wave = threadIdx.x >> 6;

    // Query fragments matching the contiguous key-segment layout.
    const float4 q0 = *(const float4*)(query + lane * 4);
    const float4 q1 = *(const float4*)(query + 256 + lane * 4);

    const int waveId = blockIdx.x * WAVES_PER_BLOCK + wave;
    const int row0   = waveId * ROWS_PER_WAVE;

    float m  = -FLT_MAX;
    float s  = 0.0f;
    int   mi = -1;

    if (row0 + ROWS_PER_WAVE <= n) {
        // -------- fast path: full tile, software-pipelined --------
        const float* kp = keys + (size_t)row0 * DIM;

        float4 ka[CHUNK], kb[CHUNK];
        #pragma unroll
        for (int r = 0; r < CHUNK; ++r) {
            ka[r] = *(const float4*)(kp + r * DIM + lane * 4);
            kb[r] = *(const float4*)(kp + r * DIM + 256 + lane * 4);
        }

        int rowc = row0;
        #pragma unroll 1
        for (int c = 0; c < NCHUNK; ++c) {
            // Prefetch next chunk while this chunk reduces.
            float4 na[CHUNK], nb[CHUNK];
            const bool more = (c + 1 < NCHUNK);
            if (more) {
                const float* np = kp + (c + 1) * CHUNK * DIM;
                #pragma unroll
                for (int r = 0; r < CHUNK; ++r) {
                    na[r] = *(const float4*)(np + r * DIM + lane * 4);
                    nb[r] = *(const float4*)(np + r * DIM + 256 + lane * 4);
                }
            }

            float d[CHUNK];
            #pragma unroll
            for (int r = 0; r < CHUNK; ++r)
                d[r] = ka[r].x*q0.x + ka[r].y*q0.y + ka[r].z*q0.z + ka[r].w*q0.w
                     + kb[r].x*q1.x + kb[r].y*q1.y + kb[r].z*q1.z + kb[r].w*q1.w;

            // Interleaved butterflies: 4 independent chains between the
            // dependent shfl steps.
            #pragma unroll
            for (int off = 32; off > 0; off >>= 1) {
                #pragma unroll
                for (int r = 0; r < CHUNK; ++r)
                    d[r] += __shfl_xor(d[r], off, 64);
            }

            // Branchless online-softmax update (wave-uniform values).
            #pragma unroll
            for (int r = 0; r < CHUNK; ++r) {
                const float dv = d[r];
                const float dm = fmaxf(m, dv);
                const float e  = expf(fminf(m, dv) - dm);  // exp(-inf)=0 on 1st
                const bool  g  = dv > m;
                s  = g ? fmaf(s, e, 1.0f) : (s + e);
                mi = g ? (rowc + r) : mi;
                m  = dm;
            }
            rowc += CHUNK;

            if (more) {
                #pragma unroll
                for (int r = 0; r < CHUNK; ++r) { ka[r] = na[r]; kb[r] = nb[r]; }
            }
        }
    } else {
        // -------- tail path (never taken at n=262144) --------
        for (int r = 0; r < ROWS_PER_WAVE; ++r) {
            const int row = row0 + r;
            if (row >= n) break;
            const float* kp = keys + (size_t)row * DIM;
            const float4 k0 = *(const float4*)(kp + lane * 4);
            const float4 k1 = *(const float4*)(kp + 256 + lane * 4);
            float d = k0.x*q0.x + k0.y*q0.y + k0.z*q0.z + k0.w*q0.w
                    + k1.x*q1.x + k1.y*q1.y + k1.z*q1.z + k1.w*q1.w;
            #pragma unroll
            for (int off = 32; off > 0; off >>= 1)
                d += __shfl_xor(d, off, 64);
            const float dm = fmaxf(m, d);
            const float e  = expf(fminf(m, d) - dm);
            const bool  g  = d > m;
            s  = g ? fmaf(s, e, 1.0f) : (s + e);
            mi = g ? row : mi;
            m  = dm;
        }
    }

    // Combine the block's 4 waves.
    __shared__ float sm[WAVES_PER_BLOCK];
    __shared__ float ss[WAVES_PER_BLOCK];
    __shared__ int   si[WAVES_PER_BLOCK];
    if (lane == 0) { sm[wave] = m; ss[wave] = s; si[wave] = mi; }
    __syncthreads();
    if (threadIdx.x == 0) {
        float M = sm[0]; int I = si[0];
        #pragma unroll
        for (int w = 1; w < WAVES_PER_BLOCK; ++w)
            if (sm[w] > M) { M = sm[w]; I = si[w]; }
        float S = 0.0f;
        #pragma unroll
        for (int w = 0; w < WAVES_PER_BLOCK; ++w)
            S += ss[w] * expf(sm[w] - M);
        pmax[blockIdx.x] = M;
        psum[blockIdx.x] = S;
        pidx[blockIdx.x] = I;
    }
}

// Kernel B: single block. Reduce the per-block partials to the global max /
// argmax / softmax denominator, then emit out = values[argmax] / denom.
__global__ __launch_bounds__(512) void finalize(
    const float* __restrict__ pmax,
    const float* __restrict__ psum,
    const int*   __restrict__ pidx,
    int nb,
    const float* __restrict__ values,
    float* __restrict__ out)
{
    __shared__ float sm[512];
    __shared__ int   si[512];
    __shared__ float ssum[512];

    const int tid = threadIdx.x;

    // Pass 1: global max + argmax.
    float m = -FLT_MAX; int mi = -1;
    for (int b = tid; b < nb; b += 512) {
        const float mb = pmax[b];
        if (mb > m) { m = mb; mi = pidx[b]; }
    }
    sm[tid] = m; si[tid] = mi;
    __syncthreads();
    #pragma unroll
    for (int off = 256; off > 0; off >>= 1) {
        if (tid < off) {
            if (sm[tid + off] > sm[tid]) { sm[tid] = sm[tid + off]; si[tid] = si[tid + off]; }
        }
        __syncthreads();
    }
    const float M = sm[0];
    const int   I = si[0];

    // Pass 2: denominator = sum_b s_b * exp(m_b - M).
    float s = 0.0f;
    for (int b = tid; b < nb; b += 512)
        s += psum[b] * expf(pmax[b] - M);
    ssum[tid] = s;
    __syncthreads();
    #pragma unroll
    for (int off = 256; off > 0; off >>= 1) {
        if (tid < off) ssum[tid] += ssum[tid + off];
        __syncthreads();
    }
    const float inv = 1.0f / ssum[0];

    // Output: values[argmax] scaled by 1/denom.
    for (int v = tid; v < VDIM; v += 512)
        out[v] = values[(size_t)I * VDIM + v] * inv;
}

extern "C" void kernel_launch(void* const* d_in, const int* in_sizes, int n_in,
                              void* d_out, int out_size, void* d_ws, size_t ws_size,
                              hipStream_t stream) {
    const float* query  = (const float*)d_in[0];
    const float* keys   = (const float*)d_in[1];
    const float* values = (const float*)d_in[2];
    float* out = (float*)d_out;

    const int n = in_sizes[1] / DIM;  // 262144

    const int rowsPerBlock = ROWS_PER_WAVE * WAVES_PER_BLOCK;  // 128
    const int nb = (n + rowsPerBlock - 1) / rowsPerBlock;      // 2048

    float* pmax = (float*)d_ws;
    float* psum = pmax + nb;
    int*   pidx = (int*)(psum + nb);

    logits_partials<<<nb, 256, 0, stream>>>(query, keys, n, pmax, psum, pidx);
    finalize<<<1, 512, 0, stream>>>(pmax, psum, pidx, nb, values, out);
}

// Round 2
// 879.763 us; speedup vs baseline: 1.0087x; 1.0016x over previous
//
#include <hip/hip_runtime.h>
#include <float.h>
#include <math.h>

#define DIM 512
#define VDIM 512
#define ROWS_PER_WAVE 32
#define WAVES_PER_BLOCK 4

// Kernel A layout: 16 lanes per row, 4 rows per load instruction.
//   sub = lane & 15  -> which 16B segment of the row this lane reads
//   rg  = lane >> 4  -> which row of the current 4-row group this lane owns
// Each wave covers 32 rows = 8 groups of 4. Per (group g, pass p) one
// global_load_dwordx4 covers 4 rows x 64 floats (4 dense 256B segments).
// acc[g] is a PER-LANE partial: no cross-lane communication in the hot loop,
// so all 64 loads per tile are independent and the compiler can keep many in
// flight. Cross-lane reduction happens ONCE at the end: 4 butterfly steps
// (xor 1,2,4,8) over 8 independent chains (32 shuffles total, fully
// pipelined), vs the old structure's 192 shuffles serialized 6-deep inside
// the per-row online-softmax chain.
__global__ __launch_bounds__(256) void logits_partials(
    const float* __restrict__ query,
    const float* __restrict__ keys,
    int n,
    float* __restrict__ pmax,
    float* __restrict__ psum,
    int*   __restrict__ pidx)
{
    const int lane = threadIdx.x & 63;
    const int wave = threadIdx.x >> 6;
    const int sub  = lane & 15;
    const int rg   = lane >> 4;

    // Query fragments: pass p needs q[p*64 + sub*4 .. +4). 8 float4 = 32 VGPR.
    float4 q[8];
    #pragma unroll
    for (int p = 0; p < 8; ++p)
        q[p] = *(const float4*)(query + p * 64 + sub * 4);

    const int waveId = blockIdx.x * WAVES_PER_BLOCK + wave;
    const int row0   = waveId * ROWS_PER_WAVE;

    float acc[8];
    #pragma unroll
    for (int g = 0; g < 8; ++g) acc[g] = 0.0f;

    bool rowValid[8];
    #pragma unroll
    for (int g = 0; g < 8; ++g) rowValid[g] = true;

    if (row0 + ROWS_PER_WAVE <= n) {
        // -------- fast path: full tile, straight-line 64 loads + 64 FMA4 ----
        const float* kbase = keys + (size_t)row0 * DIM + (size_t)rg * DIM + sub * 4;
        #pragma unroll
        for (int p = 0; p < 8; ++p) {
            float4 k[8];
            #pragma unroll
            for (int g = 0; g < 8; ++g)
                k[g] = *(const float4*)(kbase + g * (4 * DIM) + p * 64);
            #pragma unroll
            for (int g = 0; g < 8; ++g) {
                acc[g] = fmaf(k[g].x, q[p].x, acc[g]);
                acc[g] = fmaf(k[g].y, q[p].y, acc[g]);
                acc[g] = fmaf(k[g].z, q[p].z, acc[g]);
                acc[g] = fmaf(k[g].w, q[p].w, acc[g]);
            }
        }
    } else {
        // -------- tail path (never taken at n=262144) -----------------------
        #pragma unroll
        for (int g = 0; g < 8; ++g) {
            const int row = row0 + g * 4 + rg;
            if (row < n) {
                const float* kp = keys + (size_t)row * DIM + sub * 4;
                #pragma unroll
                for (int p = 0; p < 8; ++p) {
                    const float4 k = *(const float4*)(kp + p * 64);
                    acc[g] = fmaf(k.x, q[p].x, acc[g]);
                    acc[g] = fmaf(k.y, q[p].y, acc[g]);
                    acc[g] = fmaf(k.z, q[p].z, acc[g]);
                    acc[g] = fmaf(k.w, q[p].w, acc[g]);
                }
            } else {
                rowValid[g] = false;
            }
        }
    }

    // One-shot cross-lane reduce over the 16-lane sub dimension:
    // 4 steps x 8 independent chains.
    #pragma unroll
    for (int off = 1; off < 16; off <<= 1) {
        #pragma unroll
        for (int g = 0; g < 8; ++g)
            acc[g] += __shfl_xor(acc[g], off, 64);
    }

    // Per-lane online softmax over this lane's 8 rows (row = row0 + g*4 + rg).
    float m = -FLT_MAX, s = 0.0f;
    int mi = -1;
    #pragma unroll
    for (int g = 0; g < 8; ++g) {
        const float dv = rowValid[g] ? acc[g] : -FLT_MAX;
        const float dm = fmaxf(m, dv);
        const float e  = expf(fminf(m, dv) - dm);   // exp(-inf)=0 on first hit
        const bool  gt = dv > m;
        s  = gt ? fmaf(s, e, 1.0f) : (s + e);
        mi = gt ? (row0 + g * 4 + rg) : mi;
        m  = dm;
    }

    // Merge the 4 rg-group states across the wave (xor 16, then 32).
    // Symmetric, deterministic tie-break on the smaller row index.
    #pragma unroll
    for (int off = 16; off <= 32; off <<= 1) {
        const float m2 = __shfl_xor(m, off, 64);
        const float s2 = __shfl_xor(s, off, 64);
        const int  mi2 = __shfl_xor(mi, off, 64);
        const float M  = fmaxf(m, m2);
        const float S  = s * expf(m - M) + s2 * expf(m2 - M);
        mi = (m2 > m || (m2 == m && mi2 >= 0 && (mi < 0 || mi2 < mi))) ? mi2 : mi;
        m = M; s = S;
    }

    // Combine the block's 4 waves (all lanes of a wave now agree).
    __shared__ float sm[WAVES_PER_BLOCK];
    __shared__ float ss[WAVES_PER_BLOCK];
    __shared__ int   si[WAVES_PER_BLOCK];
    if (lane == 0) { sm[wave] = m; ss[wave] = s; si[wave] = mi; }
    __syncthreads();
    if (threadIdx.x == 0) {
        float M = sm[0]; int I = si[0];
        #pragma unroll
        for (int w = 1; w < WAVES_PER_BLOCK; ++w)
            if (sm[w] > M) { M = sm[w]; I = si[w]; }
        float S = 0.0f;
        #pragma unroll
        for (int w = 0; w < WAVES_PER_BLOCK; ++w)
            S += ss[w] * expf(sm[w] - M);
        pmax[blockIdx.x] = M;
        psum[blockIdx.x] = S;
        pidx[blockIdx.x] = I;
    }
}

// Kernel B: single block. Reduce the per-block partials to the global max /
// argmax / softmax denominator, then emit out = values[argmax] / denom.
__global__ __launch_bounds__(512) void finalize(
    const float* __restrict__ pmax,
    const float* __restrict__ psum,
    const int*   __restrict__ pidx,
    int nb,
    const float* __restrict__ values,
    float* __restrict__ out)
{
    __shared__ float sm[512];
    __shared__ int   si[512];
    __shared__ float ssum[512];

    const int tid = threadIdx.x;

    // Pass 1: global max + argmax.
    float m = -FLT_MAX; int mi = -1;
    for (int b = tid; b < nb; b += 512) {
        const float mb = pmax[b];
        if (mb > m) { m = mb; mi = pidx[b]; }
    }
    sm[tid] = m; si[tid] = mi;
    __syncthreads();
    #pragma unroll
    for (int off = 256; off > 0; off >>= 1) {
        if (tid < off) {
            if (sm[tid + off] > sm[tid]) { sm[tid] = sm[tid + off]; si[tid] = si[tid + off]; }
        }
        __syncthreads();
    }
    const float M = sm[0];
    const int   I = si[0];

    // Pass 2: denominator = sum_b s_b * exp(m_b - M).
    float s = 0.0f;
    for (int b = tid; b < nb; b += 512)
        s += psum[b] * expf(pmax[b] - M);
    ssum[tid] = s;
    __syncthreads();
    #pragma unroll
    for (int off = 256; off > 0; off >>= 1) {
        if (tid < off) ssum[tid] += ssum[tid + off];
        __syncthreads();
    }
    const float inv = 1.0f / ssum[0];

    // Output: values[argmax] scaled by 1/denom.
    for (int v = tid; v < VDIM; v += 512)
        out[v] = values[(size_t)I * VDIM + v] * inv;
}

extern "C" void kernel_launch(void* const* d_in, const int* in_sizes, int n_in,
                              void* d_out, int out_size, void* d_ws, size_t ws_size,
                              hipStream_t stream) {
    const float* query  = (const float*)d_in[0];
    const float* keys   = (const float*)d_in[1];
    const float* values = (const float*)d_in[2];
    float* out = (float*)d_out;

    const int n = in_sizes[1] / DIM;  // 262144

    const int rowsPerBlock = ROWS_PER_WAVE * WAVES_PER_BLOCK;  // 128
    const int nb = (n + rowsPerBlock - 1) / rowsPerBlock;      // 2048

    float* pmax = (float*)d_ws;
    float* psum = pmax + nb;
    int*   pidx = (int*)(psum + nb);

    logits_partials<<<nb, 256, 0, stream>>>(query, keys, n, pmax, psum, pidx);
    finalize<<<1, 512, 0, stream>>>(pmax, psum, pidx, nb, values, out);
}